// Round 1
// 957.122 us; speedup vs baseline: 1.7798x; 1.7798x over previous
//
#include <hip/hip_runtime.h>
#include <hip/hip_bf16.h>

// Problem: B=8192 rows, D=4096. 3 layers of relu(l2norm(h) @ W^T + b).
// GEMM rewritten as the 256x256 8-phase pipelined template:
//   BK=64, 8 waves (512 thr), 128 KiB LDS double-buffer, counted vmcnt(6)
//   (never drain-to-0 in steady state), raw s_barrier (no __syncthreads
//   drain), setprio around MFMA clusters, chunk-major LDS (conflict-free
//   ds_read_b128, verified SQ_LDS_BANK_CONFLICT=0 on this layout).

#define NROWS 8192
#define DIM   4096

typedef __bf16 bf16x8 __attribute__((ext_vector_type(8)));
typedef float  f32x4  __attribute__((ext_vector_type(4)));

__device__ static inline short f2bf(float f) {
  __hip_bfloat16 h = __float2bfloat16(f);
  return __builtin_bit_cast(short, h);
}

// raw barrier: compiler fence + s_barrier, NO vmcnt/lgkmcnt drain
#define BARRIER() do { asm volatile("" ::: "memory"); \
                       __builtin_amdgcn_s_barrier();  \
                       asm volatile("" ::: "memory"); } while (0)

// ---------------------------------------------------------------------------
// C[M,N] = relu(A[M,K](bf16) . Bw[N,K](bf16)^T + bias[N]), fp32 out.
// Tile 256x256, BK=64. 8 waves in 2(M)x4(N) grid; each wave owns 128x64 out
// = acc[8][4] 16x16 fragments. LDS per operand tile: 2048 16B units,
// unit u = kchunk*256 + row (kchunk = wave id staging it, 8 chunks of 8 bf16).
// Fragment reads: lanes 0..15 hit consecutive units -> conflict-free b128.
//
// Schedule per K-tile t (buffer d = t&1), 4 phases x {stage | bar | mfma | bar}:
//   ph0: ds_read aF[0..3][2], bF[0..3][2] (16 reads) ; stage (t+1, A.h1)
//        -> after ph0, B region of buf d is fully consumed (regs)
//   ph1: stage (t+2, B.h0) into buf d   [legal: B reads done + barrier]
//   ph2: ds_read aF[4..7][2] ; stage (t+2, B.h1)
//        -> after ph2, A region of buf d fully consumed
//   ph3: stage (t+2, A.h0) ; MFMA ; s_waitcnt vmcnt(6) ; barrier
//        vmcnt(6) = 3 half-tiles (2 loads/thr each) in flight -> tile t+1
//        fully landed, tile t+2 halves B0,B1,A0 still flying. (t+1,A.h1)
//        is staged at ph0 of tile t+1 -> 4th-newest at the next wait.
// Prologue: tile0 {B0,B1,A0,A1} + tile1 {B0,B1,A0}, vmcnt(6).
// Tail: t >= NT-2 drains vmcnt(0).
// ---------------------------------------------------------------------------
__global__ __launch_bounds__(512, 2)
void gemm256_bias_relu(const short* __restrict__ A,
                       const short* __restrict__ Bw,
                       const float* __restrict__ bias,
                       float* __restrict__ C,
                       int M, int N, int K)
{
  __shared__ short lds[4][16384];   // [buf*2+op][2048 units * 8 shorts] = 128 KiB

  // XCD-aware swizzle (bijective: 512 % 8 == 0)
  int bid = blockIdx.x;
  const int nwg = gridDim.x;
  if ((nwg & 7) == 0) { const int cpx = nwg >> 3; bid = (bid & 7) * cpx + (bid >> 3); }
  const int nbn  = N >> 8;
  const int brow = (bid / nbn) << 8;
  const int bcol = (bid % nbn) << 8;

  const int lane = threadIdx.x & 63;
  const int wid  = threadIdx.x >> 6;   // 0..7 : stages k-chunk `wid`
  const int wr   = wid >> 2;           // 0..1 : 128-row output band
  const int wc   = wid & 3;            // 0..3 : 64-col output band

  // bias first so these VMEM loads are oldest in the vmcnt queue
  float bv[4];
#pragma unroll
  for (int j = 0; j < 4; ++j)
    bv[j] = bias[bcol + wc * 64 + j * 16 + (lane & 15)];

  f32x4 acc[8][4] = {};

  const size_t Kz   = (size_t)K;
  const size_t rowK = Kz * 2;          // bytes per row
  const char*  Ag   = (const char*)A;
  const char*  Bg   = (const char*)Bw;
  char* const  ldsB = (char*)&lds[0][0];

  // per-lane global byte offset of (row = base+lane, k = wid*8)
  const size_t gAl = ((size_t)(brow + lane) * Kz + (size_t)(wid * 8)) * 2;
  const size_t gBl = ((size_t)(bcol + lane) * Kz + (size_t)(wid * 8)) * 2;
  const int ldst_base = wid * 256 * 16;   // wave's k-chunk slot (bytes)

  // stage one 128-row half (2 x global_load_lds x16B per thread)
  auto stage_half = [&](int tile, int op, int h) {
    const char*  gp = op ? Bg : Ag;
    const size_t gt = (op ? gBl : gAl) + (size_t)tile * 128;  // tile*64 elems *2B
    char* lb = ldsB + ((tile & 1) * 2 + op) * 32768 + ldst_base;
#pragma unroll
    for (int s = 0; s < 2; ++s) {
      const int r = h * 128 + s * 64;   // + lane rows, linear in LDS units
      __builtin_amdgcn_global_load_lds(
          (const __attribute__((address_space(1))) void*)(gp + gt + (size_t)r * rowK),
          (__attribute__((address_space(3))) void*)(lb + r * 16), 16, 0, 0);
    }
  };

  // fragment base byte offsets within an operand tile
  const int aoffb = ((lane >> 4) * 256 + wr * 128 + (lane & 15)) * 16;
  const int boffb = ((lane >> 4) * 256 + wc * 64  + (lane & 15)) * 16;

  const int NT = K >> 6;

  // ---- prologue ----
  stage_half(0, 1, 0); stage_half(0, 1, 1);
  stage_half(0, 0, 0); stage_half(0, 0, 1);
  if (NT > 1) { stage_half(1, 1, 0); stage_half(1, 1, 1); stage_half(1, 0, 0); }
  if (NT > 1) asm volatile("s_waitcnt vmcnt(6)" ::: "memory");
  else        asm volatile("s_waitcnt vmcnt(0)" ::: "memory");
  BARRIER();

  bf16x8 aF[4][2], bF[4][2];

#define MFMA_QUAD(I0, J0)                                                    \
  _Pragma("unroll")                                                          \
  for (int i = 0; i < 4; ++i)                                                \
    _Pragma("unroll")                                                        \
    for (int j = 0; j < 2; ++j)                                              \
      _Pragma("unroll")                                                      \
      for (int ks = 0; ks < 2; ++ks)                                         \
        acc[(I0) + i][(J0) + j] = __builtin_amdgcn_mfma_f32_16x16x32_bf16(   \
            aF[i][ks], bF[(J0) + j][ks], acc[(I0) + i][(J0) + j], 0, 0, 0);

  for (int t = 0; t < NT; ++t) {
    const char* At = ldsB + ((t & 1) * 2 + 0) * 32768;
    const char* Bt = ldsB + ((t & 1) * 2 + 1) * 32768;

    // ---- phase 0 ----
#pragma unroll
    for (int i = 0; i < 4; ++i)
#pragma unroll
      for (int ks = 0; ks < 2; ++ks)
        aF[i][ks] = *reinterpret_cast<const bf16x8*>(At + aoffb + ks * 16384 + i * 256);
#pragma unroll
    for (int j = 0; j < 4; ++j)
#pragma unroll
      for (int ks = 0; ks < 2; ++ks)
        bF[j][ks] = *reinterpret_cast<const bf16x8*>(Bt + boffb + ks * 16384 + j * 256);
    if (t + 1 < NT) stage_half(t + 1, 0, 1);
    BARRIER();
    asm volatile("s_waitcnt lgkmcnt(0)" ::: "memory");
    __builtin_amdgcn_s_setprio(1);
    MFMA_QUAD(0, 0)
    __builtin_amdgcn_s_setprio(0);
    BARRIER();

    // ---- phase 1 ----
    if (t + 2 < NT) stage_half(t + 2, 1, 0);
    BARRIER();
    __builtin_amdgcn_s_setprio(1);
    MFMA_QUAD(0, 2)
    __builtin_amdgcn_s_setprio(0);
    BARRIER();

    // ---- phase 2 ----
#pragma unroll
    for (int i = 0; i < 4; ++i)
#pragma unroll
      for (int ks = 0; ks < 2; ++ks)
        aF[i][ks] = *reinterpret_cast<const bf16x8*>(At + aoffb + ks * 16384 + (i + 4) * 256);
    if (t + 2 < NT) stage_half(t + 2, 1, 1);
    BARRIER();
    asm volatile("s_waitcnt lgkmcnt(0)" ::: "memory");
    __builtin_amdgcn_s_setprio(1);
    MFMA_QUAD(4, 0)
    __builtin_amdgcn_s_setprio(0);
    BARRIER();

    // ---- phase 3 ----
    if (t + 2 < NT) stage_half(t + 2, 0, 0);
    BARRIER();
    __builtin_amdgcn_s_setprio(1);
    MFMA_QUAD(4, 2)
    __builtin_amdgcn_s_setprio(0);
    if (t >= NT - 2) asm volatile("s_waitcnt vmcnt(0)" ::: "memory");
    else             asm volatile("s_waitcnt vmcnt(6)" ::: "memory");
    BARRIER();
  }
#undef MFMA_QUAD

  // epilogue: C/D layout col = lane&15, row = (lane>>4)*4 + reg
#pragma unroll
  for (int i = 0; i < 8; ++i) {
    const int rbase = brow + wr * 128 + i * 16 + ((lane >> 4) << 2);
#pragma unroll
    for (int j = 0; j < 4; ++j) {
      const int col = bcol + wc * 64 + j * 16 + (lane & 15);
#pragma unroll
      for (int r = 0; r < 4; ++r) {
        const float v = acc[i][j][r] + bv[j];
        C[(size_t)(rbase + r) * N + col] = v > 0.f ? v : 0.f;
      }
    }
  }
}

// ---------------------------------------------------------------------------
// Row L2-normalize (fp32 in) -> bf16 out. One block (256 thr) per row of 4096.
// ---------------------------------------------------------------------------
__global__ __launch_bounds__(256)
void rownorm_bf16(const float* __restrict__ in, short* __restrict__ out)
{
  const int row = blockIdx.x;
  const int t0  = threadIdx.x;
  const float4* inr = (const float4*)(in + (size_t)row * DIM);

  float4 v[4];
  float ss = 0.f;
#pragma unroll
  for (int t = 0; t < 4; ++t) {
    v[t] = inr[t0 + t * 256];
    ss += v[t].x * v[t].x + v[t].y * v[t].y + v[t].z * v[t].z + v[t].w * v[t].w;
  }
#pragma unroll
  for (int off = 32; off > 0; off >>= 1)
    ss += __shfl_down(ss, off, 64);

  __shared__ float wss[4];
  if ((t0 & 63) == 0) wss[t0 >> 6] = ss;
  __syncthreads();
  const float tot   = wss[0] + wss[1] + wss[2] + wss[3];
  const float scale = 1.f / fmaxf(sqrtf(tot), 1e-12f);  // F.normalize eps

  short4* outr = (short4*)(out + (size_t)row * DIM);
#pragma unroll
  for (int t = 0; t < 4; ++t) {
    short4 o;
    o.x = f2bf(v[t].x * scale);
    o.y = f2bf(v[t].y * scale);
    o.z = f2bf(v[t].z * scale);
    o.w = f2bf(v[t].w * scale);
    outr[t0 + t * 256] = o;
  }
}

// ---------------------------------------------------------------------------
// fp32 -> bf16 bulk cast (for W), vectorized, grid-stride.
// ---------------------------------------------------------------------------
__global__ __launch_bounds__(256)
void cast_bf16(const float* __restrict__ in, short* __restrict__ out, int n4)
{
  int i = blockIdx.x * 256 + threadIdx.x;
  const int stride = gridDim.x * 256;
  for (; i < n4; i += stride) {
    const float4 v = ((const float4*)in)[i];
    short4 o;
    o.x = f2bf(v.x);
    o.y = f2bf(v.y);
    o.z = f2bf(v.z);
    o.w = f2bf(v.w);
    ((short4*)out)[i] = o;
  }
}

extern "C" void kernel_launch(void* const* d_in, const int* in_sizes, int n_in,
                              void* d_out, int out_size, void* d_ws, size_t ws_size,
                              hipStream_t stream) {
  const float* x = (const float*)d_in[0];
  const float* W[3]    = { (const float*)d_in[1], (const float*)d_in[3], (const float*)d_in[5] };
  const float* bias[3] = { (const float*)d_in[2], (const float*)d_in[4], (const float*)d_in[6] };
  float* out = (float*)d_out;

  // workspace layout: hn bf16 [8192][4096] (64 MiB) | Wb bf16 [4096][4096] (32 MiB)
  short* hn = (short*)d_ws;
  short* Wb = (short*)((char*)d_ws + (size_t)NROWS * DIM * 2);

  const size_t layer_elems = (size_t)NROWS * DIM;
  const float* hin = x;

  for (int L = 0; L < 3; ++L) {
    cast_bf16<<<2048, 256, 0, stream>>>(W[L], Wb, DIM * DIM / 4);
    rownorm_bf16<<<NROWS, 256, 0, stream>>>(hin, hn);
    gemm256_bias_relu<<<(NROWS / 256) * (DIM / 256), 512, 0, stream>>>(
        hn, Wb, bias[L], out + (size_t)L * layer_elems, NROWS, DIM, DIM);
    hin = out + (size_t)L * layer_elems;
  }
}

// Round 2
// 855.272 us; speedup vs baseline: 1.9918x; 1.1191x over previous
//
#include <hip/hip_runtime.h>
#include <hip/hip_bf16.h>

// Problem: B=8192 rows, D=4096. 3 layers of relu(l2norm(h) @ W^T + b).
// GEMM: 256x256 tile, BK=64, 8 waves, 128 KiB LDS double-buffer, 4 phases
// per K-tile with 1 half-tile stage per phase, counted vmcnt(4), raw
// s_barrier, setprio around MFMA clusters.
// LAYOUT (this round's change): coalesced staging + XOR-swizzled LDS.
//   LDS tile: [row][kc] row-major, 128 B rows (kc = 16B chunk 0..7).
//   Stage: lane -> row base+(l>>3), SRC chunk (l&7)^(l>>3); linear LDS dest.
//   Read:  phys kc = logical kc ^ (row&7)  (same involution both sides).
// This replaces the chunk-major layout whose staging was 64-way lane-
// scattered (64 cache lines / wave-load -> TA-pipe bound, MfmaUtil 39%).

#define NROWS 8192
#define DIM   4096

typedef __bf16 bf16x8 __attribute__((ext_vector_type(8)));
typedef float  f32x4  __attribute__((ext_vector_type(4)));

__device__ static inline short f2bf(float f) {
  __hip_bfloat16 h = __float2bfloat16(f);
  return __builtin_bit_cast(short, h);
}

// raw barrier: compiler fence + s_barrier, NO vmcnt/lgkmcnt drain
#define BARRIER() do { asm volatile("" ::: "memory"); \
                       __builtin_amdgcn_s_barrier();  \
                       asm volatile("" ::: "memory"); } while (0)

// ---------------------------------------------------------------------------
// C[M,N] = relu(A[M,K](bf16) . Bw[N,K](bf16)^T + bias[N]), fp32 out.
// 8 waves in 2(M)x4(N); per-wave out 128x64 = acc[8][4] 16x16 frags.
//
// Per K-tile t (buf d = t&1), 4 phases:
//  ph0: read aF[0..1], bF[0..3] (12 ds_read_b128); stage A(t+1).h0
//  ph1: read aF[2..3];                             stage A(t+1).h1
//  ph2: read aF[4..5];                             stage B(t+2).h0
//  ph3: read aF[6..7];                             stage B(t+2).h1
//  each phase: {reads; stage; barrier; lgkmcnt(0); setprio1; 16 MFMA;
//               setprio0; barrier}; end of ph3 additionally vmcnt(4).
// Lifetimes: B(t) fully read in ph0 -> B region restageable from ph2 (same
// buf, (t+2)&1 == t&1). A(t) read through ph3; A(t+1) goes to OTHER buf,
// whose A(t-1) was consumed by end of t-1. vmcnt(4) leaves only B(t+2)'s
// 4 loads in flight -> A(t+1) (this tile) and B(t+1) (prev tile) landed.
// Prologue: A0.h0,A0.h1,B0.h0,B0.h1,B1.h0,B1.h1 then vmcnt(4).
// ---------------------------------------------------------------------------
__global__ __launch_bounds__(512, 2)
void gemm256_bias_relu(const short* __restrict__ A,
                       const short* __restrict__ Bw,
                       const float* __restrict__ bias,
                       float* __restrict__ C,
                       int M, int N, int K)
{
  __shared__ short lds[4][16384];   // [buf*2+op][256 rows * 64 bf16] = 128 KiB

  // XCD-aware swizzle (bijective: grid % 8 == 0 here)
  int bid = blockIdx.x;
  const int nwg = gridDim.x;
  if ((nwg & 7) == 0) { const int cpx = nwg >> 3; bid = (bid & 7) * cpx + (bid >> 3); }
  const int nbn  = N >> 8;
  const int brow = (bid / nbn) << 8;
  const int bcol = (bid % nbn) << 8;

  const int lane = threadIdx.x & 63;
  const int wid  = threadIdx.x >> 6;   // 0..7
  const int wr   = wid >> 2;           // 0..1 : 128-row output band
  const int wc   = wid & 3;            // 0..3 : 64-col output band

  // bias (issued before stage loads; any reorder only strengthens waits)
  float bv[4];
#pragma unroll
  for (int j = 0; j < 4; ++j)
    bv[j] = bias[bcol + wc * 64 + j * 16 + (lane & 15)];

  f32x4 acc[8][4] = {};

  const size_t Kz   = (size_t)K;
  const size_t rowK = Kz * 2;          // bytes per global row
  const char*  Ag   = (const char*)A;
  const char*  Bg   = (const char*)Bw;
  char* const  ldsB = (char*)&lds[0][0];

  // ---- staging addressing (coalesced, source pre-swizzled) ----
  // wave-load covers 8 rows x 128 B; lane: row +(l>>3), src chunk (l&7)^(l>>3)
  const int r8  = lane >> 3;
  const int kcs = (lane & 7) ^ r8;
  const size_t gAl = (size_t)(brow + r8) * rowK + (size_t)kcs * 16;
  const size_t gBl = (size_t)(bcol + r8) * rowK + (size_t)kcs * 16;

  // stage one 128-row half: 2 x global_load_lds(16B) per thread
  auto stage_half = [&](int tile, int op, int h) {
    const char*  gp = op ? Bg : Ag;
    const size_t gt = (op ? gBl : gAl) + (size_t)tile * 128;  // k-advance bytes
    char* lb = ldsB + ((tile & 1) * 2 + op) * 32768;
#pragma unroll
    for (int s = 0; s < 2; ++s) {
      const int rb = h * 128 + s * 64 + wid * 8;  // row-block base (8 rows)
      __builtin_amdgcn_global_load_lds(
          (const __attribute__((address_space(1))) void*)(gp + gt + (size_t)rb * rowK),
          (__attribute__((address_space(3))) void*)(lb + rb * 128), 16, 0, 0);
    }
  };

  // ---- fragment read addressing (swizzled) ----
  // logical kc = ks*4 + (lane>>4); phys kc = kc ^ (row&7), row&7 == lane&7.
  // byte = row*128 + ((lane>>4)^(lane&3))*16 + ((ks ^ ((lane>>2)&1))<<6)
  const int l15  = lane & 15;
  const int xlo  = ((lane >> 4) ^ (lane & 3)) * 16;
  const int b2   = (lane >> 2) & 1;
  const int k64[2] = { b2 << 6, (1 - b2) << 6 };
  const int abase = (wr * 128 + l15) * 128 + xlo;
  const int bbase = (wc * 64  + l15) * 128 + xlo;

  const int NT = K >> 6;

  // ---- prologue ----
  stage_half(0, 0, 0); stage_half(0, 0, 1);
  stage_half(0, 1, 0); stage_half(0, 1, 1);
  if (NT > 1) { stage_half(1, 1, 0); stage_half(1, 1, 1); }
  if (NT > 1) asm volatile("s_waitcnt vmcnt(4)" ::: "memory");
  else        asm volatile("s_waitcnt vmcnt(0)" ::: "memory");
  BARRIER();

  bf16x8 aF[2][2], bF[4][2];

#define MFMA2(I0)                                                            \
  _Pragma("unroll")                                                          \
  for (int ii = 0; ii < 2; ++ii)                                             \
    _Pragma("unroll")                                                        \
    for (int j = 0; j < 4; ++j)                                              \
      _Pragma("unroll")                                                      \
      for (int ks = 0; ks < 2; ++ks)                                         \
        acc[(I0) + ii][j] = __builtin_amdgcn_mfma_f32_16x16x32_bf16(         \
            aF[ii][ks], bF[j][ks], acc[(I0) + ii][j], 0, 0, 0);

#define LOAD_A(I0)                                                           \
  _Pragma("unroll")                                                          \
  for (int ii = 0; ii < 2; ++ii)                                             \
    _Pragma("unroll")                                                        \
    for (int ks = 0; ks < 2; ++ks)                                           \
      aF[ii][ks] = *reinterpret_cast<const bf16x8*>(                         \
          At + abase + ((I0) + ii) * 2048 + k64[ks]);

  for (int t = 0; t < NT; ++t) {
    const char* At = ldsB + ((t & 1) * 2 + 0) * 32768;
    const char* Bt = ldsB + ((t & 1) * 2 + 1) * 32768;

    // ---- phase 0: all B frags + aF[0..1]; stage A(t+1).h0 ----
    LOAD_A(0)
#pragma unroll
    for (int j = 0; j < 4; ++j)
#pragma unroll
      for (int ks = 0; ks < 2; ++ks)
        bF[j][ks] = *reinterpret_cast<const bf16x8*>(Bt + bbase + j * 2048 + k64[ks]);
    if (t + 1 < NT) stage_half(t + 1, 0, 0);
    BARRIER();
    asm volatile("s_waitcnt lgkmcnt(0)" ::: "memory");
    __builtin_amdgcn_s_setprio(1);
    MFMA2(0)
    __builtin_amdgcn_s_setprio(0);
    BARRIER();

    // ---- phase 1: aF[2..3]; stage A(t+1).h1 ----
    LOAD_A(2)
    if (t + 1 < NT) stage_half(t + 1, 0, 1);
    BARRIER();
    asm volatile("s_waitcnt lgkmcnt(0)" ::: "memory");
    __builtin_amdgcn_s_setprio(1);
    MFMA2(2)
    __builtin_amdgcn_s_setprio(0);
    BARRIER();

    // ---- phase 2: aF[4..5]; stage B(t+2).h0 (B(t) reads done in ph0) ----
    LOAD_A(4)
    if (t + 2 < NT) stage_half(t + 2, 1, 0);
    BARRIER();
    asm volatile("s_waitcnt lgkmcnt(0)" ::: "memory");
    __builtin_amdgcn_s_setprio(1);
    MFMA2(4)
    __builtin_amdgcn_s_setprio(0);
    BARRIER();

    // ---- phase 3: aF[6..7]; stage B(t+2).h1; counted vmcnt ----
    LOAD_A(6)
    if (t + 2 < NT) stage_half(t + 2, 1, 1);
    BARRIER();
    asm volatile("s_waitcnt lgkmcnt(0)" ::: "memory");
    __builtin_amdgcn_s_setprio(1);
    MFMA2(6)
    __builtin_amdgcn_s_setprio(0);
    if (t >= NT - 2) asm volatile("s_waitcnt vmcnt(0)" ::: "memory");
    else             asm volatile("s_waitcnt vmcnt(4)" ::: "memory");
    BARRIER();
  }
#undef MFMA2
#undef LOAD_A

  // epilogue: C/D layout col = lane&15, row = (lane>>4)*4 + reg
#pragma unroll
  for (int i = 0; i < 8; ++i) {
    const int rbase = brow + wr * 128 + i * 16 + ((lane >> 4) << 2);
#pragma unroll
    for (int j = 0; j < 4; ++j) {
      const int col = bcol + wc * 64 + j * 16 + (lane & 15);
#pragma unroll
      for (int r = 0; r < 4; ++r) {
        const float v = acc[i][j][r] + bv[j];
        C[(size_t)(rbase + r) * N + col] = v > 0.f ? v : 0.f;
      }
    }
  }
}

// ---------------------------------------------------------------------------
// Row L2-normalize (fp32 in) -> bf16 out. One block (256 thr) per row of 4096.
// ---------------------------------------------------------------------------
__global__ __launch_bounds__(256)
void rownorm_bf16(const float* __restrict__ in, short* __restrict__ out)
{
  const int row = blockIdx.x;
  const int t0  = threadIdx.x;
  const float4* inr = (const float4*)(in + (size_t)row * DIM);

  float4 v[4];
  float ss = 0.f;
#pragma unroll
  for (int t = 0; t < 4; ++t) {
    v[t] = inr[t0 + t * 256];
    ss += v[t].x * v[t].x + v[t].y * v[t].y + v[t].z * v[t].z + v[t].w * v[t].w;
  }
#pragma unroll
  for (int off = 32; off > 0; off >>= 1)
    ss += __shfl_down(ss, off, 64);

  __shared__ float wss[4];
  if ((t0 & 63) == 0) wss[t0 >> 6] = ss;
  __syncthreads();
  const float tot   = wss[0] + wss[1] + wss[2] + wss[3];
  const float scale = 1.f / fmaxf(sqrtf(tot), 1e-12f);  // F.normalize eps

  short4* outr = (short4*)(out + (size_t)row * DIM);
#pragma unroll
  for (int t = 0; t < 4; ++t) {
    short4 o;
    o.x = f2bf(v[t].x * scale);
    o.y = f2bf(v[t].y * scale);
    o.z = f2bf(v[t].z * scale);
    o.w = f2bf(v[t].w * scale);
    outr[t0 + t * 256] = o;
  }
}

// ---------------------------------------------------------------------------
// fp32 -> bf16 bulk cast (for W), vectorized, grid-stride.
// ---------------------------------------------------------------------------
__global__ __launch_bounds__(256)
void cast_bf16(const float* __restrict__ in, short* __restrict__ out, int n4)
{
  int i = blockIdx.x * 256 + threadIdx.x;
  const int stride = gridDim.x * 256;
  for (; i < n4; i += stride) {
    const float4 v = ((const float4*)in)[i];
    short4 o;
    o.x = f2bf(v.x);
    o.y = f2bf(v.y);
    o.z = f2bf(v.z);
    o.w = f2bf(v.w);
    ((short4*)out)[i] = o;
  }
}

extern "C" void kernel_launch(void* const* d_in, const int* in_sizes, int n_in,
                              void* d_out, int out_size, void* d_ws, size_t ws_size,
                              hipStream_t stream) {
  const float* x = (const float*)d_in[0];
  const float* W[3]    = { (const float*)d_in[1], (const float*)d_in[3], (const float*)d_in[5] };
  const float* bias[3] = { (const float*)d_in[2], (const float*)d_in[4], (const float*)d_in[6] };
  float* out = (float*)d_out;

  // workspace layout: hn bf16 [8192][4096] (64 MiB) | Wb bf16 [4096][4096] (32 MiB)
  short* hn = (short*)d_ws;
  short* Wb = (short*)((char*)d_ws + (size_t)NROWS * DIM * 2);

  const size_t layer_elems = (size_t)NROWS * DIM;
  const float* hin = x;

  for (int L = 0; L < 3; ++L) {
    cast_bf16<<<2048, 256, 0, stream>>>(W[L], Wb, DIM * DIM / 4);
    rownorm_bf16<<<NROWS, 256, 0, stream>>>(hin, hn);
    gemm256_bias_relu<<<(NROWS / 256) * (DIM / 256), 512, 0, stream>>>(
        hn, Wb, bias[L], out + (size_t)L * layer_elems, NROWS, DIM, DIM);
    hin = out + (size_t)L * layer_elems;
  }
}